// Round 3
// baseline (64.909 us; speedup 1.0000x reference)
//
#include <hip/hip_runtime.h>

#define D_MODEL 512
#define D_TOK   504
#define EPS     1e-5f
#define SQRT_D  22.627416997969522f   // sqrt(512)
#define TOK_PER_WAVE 4

typedef float f32x4 __attribute__((ext_vector_type(4)));

__global__ __launch_bounds__(256) void musical_emb_kernel(
    const int*   __restrict__ x,
    const float* __restrict__ tok_tab,   // [2048][504]
    const float* __restrict__ typ_tab,   // [5][8]
    const float* __restrict__ gamma,     // [512]
    const float* __restrict__ beta,      // [512]
    float*       __restrict__ out,       // [n_tokens][512]
    int n_tokens)
{
    const int wave = (int)((blockIdx.x * blockDim.x + threadIdx.x) >> 6);
    const int lane = (int)(threadIdx.x & 63);
    const int tok0 = wave * TOK_PER_WAVE;
    if (tok0 >= n_tokens) return;

    // all lanes read the same 16B -> broadcast; then force scalar
    const int4 xv = *reinterpret_cast<const int4*>(x + tok0);
    int xi[TOK_PER_WAVE];
    xi[0] = __builtin_amdgcn_readfirstlane(xv.x);
    xi[1] = __builtin_amdgcn_readfirstlane(xv.y);
    xi[2] = __builtin_amdgcn_readfirstlane(xv.z);
    xi[3] = __builtin_amdgcn_readfirstlane(xv.w);

    // branchless row pointer per token: lane 63 reads the 8-float type row
    const float* rowp[TOK_PER_WAVE];
#pragma unroll
    for (int k = 0; k < TOK_PER_WAVE; ++k) {
        const int t = (xi[k] >= 128) + (xi[k] >= 256) + (xi[k] >= 512) + (xi[k] >= 1024);
        const float* tokrow = tok_tab + (size_t)xi[k] * D_TOK + (size_t)lane * 8;
        const float* typrow = typ_tab + (size_t)t * 8;
        rowp[k] = (lane == 63) ? typrow : tokrow;
    }

    // issue all loads before any use (ILP)
    float4 a[TOK_PER_WAVE], b[TOK_PER_WAVE];
#pragma unroll
    for (int k = 0; k < TOK_PER_WAVE; ++k) {
        a[k] = *reinterpret_cast<const float4*>(rowp[k]);
        b[k] = *reinterpret_cast<const float4*>(rowp[k] + 4);
    }

    // gamma/beta once per wave
    const float4 g0 = *reinterpret_cast<const float4*>(gamma + lane * 8);
    const float4 g1 = *reinterpret_cast<const float4*>(gamma + lane * 8 + 4);
    const float4 bb0 = *reinterpret_cast<const float4*>(beta + lane * 8);
    const float4 bb1 = *reinterpret_cast<const float4*>(beta + lane * 8 + 4);
    const float4 bs0 = make_float4(bb0.x * SQRT_D, bb0.y * SQRT_D, bb0.z * SQRT_D, bb0.w * SQRT_D);
    const float4 bs1 = make_float4(bb1.x * SQRT_D, bb1.y * SQRT_D, bb1.z * SQRT_D, bb1.w * SQRT_D);

    // 4 independent reduction chains (interleaved by the scheduler)
    float s[TOK_PER_WAVE], s2[TOK_PER_WAVE];
#pragma unroll
    for (int k = 0; k < TOK_PER_WAVE; ++k) {
        float t1 = a[k].x + a[k].y + a[k].z + a[k].w + b[k].x + b[k].y + b[k].z + b[k].w;
        float t2 = a[k].x * a[k].x + a[k].y * a[k].y + a[k].z * a[k].z + a[k].w * a[k].w
                 + b[k].x * b[k].x + b[k].y * b[k].y + b[k].z * b[k].z + b[k].w * b[k].w;
        s[k] = t1; s2[k] = t2;
    }
#pragma unroll
    for (int off = 32; off > 0; off >>= 1) {
#pragma unroll
        for (int k = 0; k < TOK_PER_WAVE; ++k) {
            s[k]  += __shfl_xor(s[k],  off, 64);
            s2[k] += __shfl_xor(s2[k], off, 64);
        }
    }

    const float inv_n = 1.0f / (float)D_MODEL;
#pragma unroll
    for (int k = 0; k < TOK_PER_WAVE; ++k) {
        const float mean = s[k] * inv_n;
        const float var  = s2[k] * inv_n - mean * mean;
        const float rs   = rsqrtf(var + EPS) * SQRT_D;

        f32x4 o0, o1;
        o0.x = (a[k].x - mean) * rs * g0.x + bs0.x;
        o0.y = (a[k].y - mean) * rs * g0.y + bs0.y;
        o0.z = (a[k].z - mean) * rs * g0.z + bs0.z;
        o0.w = (a[k].w - mean) * rs * g0.w + bs0.w;
        o1.x = (b[k].x - mean) * rs * g1.x + bs1.x;
        o1.y = (b[k].y - mean) * rs * g1.y + bs1.y;
        o1.z = (b[k].z - mean) * rs * g1.z + bs1.z;
        o1.w = (b[k].w - mean) * rs * g1.w + bs1.w;

        float* orow = out + (size_t)(tok0 + k) * D_MODEL + (size_t)lane * 8;
        __builtin_nontemporal_store(o0, reinterpret_cast<f32x4*>(orow));
        __builtin_nontemporal_store(o1, reinterpret_cast<f32x4*>(orow + 4));
    }
}

extern "C" void kernel_launch(void* const* d_in, const int* in_sizes, int n_in,
                              void* d_out, int out_size, void* d_ws, size_t ws_size,
                              hipStream_t stream) {
    const int*   x       = (const int*)d_in[0];
    const float* tok_tab = (const float*)d_in[1];
    const float* typ_tab = (const float*)d_in[2];
    const float* gamma   = (const float*)d_in[3];
    const float* beta    = (const float*)d_in[4];
    float*       out     = (float*)d_out;

    const int n_tokens = in_sizes[0];                  // 65536
    const int threads  = 256;                          // 4 waves/block
    const int tok_per_block = (threads / 64) * TOK_PER_WAVE;  // 16
    const int blocks   = (n_tokens + tok_per_block - 1) / tok_per_block;

    musical_emb_kernel<<<blocks, threads, 0, stream>>>(
        x, tok_tab, typ_tab, gamma, beta, out, n_tokens);
}

// Round 4
// 43.862 us; speedup vs baseline: 1.4798x; 1.4798x over previous
//
#include <hip/hip_runtime.h>

#define D_MODEL 512
#define D_TOK   504
#define EPS     1e-5f
#define SQRT_D  22.627416997969522f   // sqrt(512)
#define VOCAB   2048

// ---------------------------------------------------------------------------
// Kernel 1: one wave per vocab id -> unique output row table in d_ws.
// Identical math to the verified Round-1 kernel (absmax 0.125 pass).
// ---------------------------------------------------------------------------
__global__ __launch_bounds__(256) void build_table_kernel(
    const float* __restrict__ tok_tab,   // [2048][504]
    const float* __restrict__ typ_tab,   // [5][8]
    const float* __restrict__ gamma,     // [512]
    const float* __restrict__ beta,      // [512]
    float*       __restrict__ uniq)      // [2048][512]
{
    const int vid  = (int)((blockIdx.x * blockDim.x + threadIdx.x) >> 6);
    const int lane = (int)(threadIdx.x & 63);
    if (vid >= VOCAB) return;

    const int t = (vid >= 128) + (vid >= 256) + (vid >= 512) + (vid >= 1024);

    float v[8];
    if (lane < 63) {
        const float* row = tok_tab + (size_t)vid * D_TOK + (size_t)lane * 8;
        const float4 a = *reinterpret_cast<const float4*>(row);
        const float4 b = *reinterpret_cast<const float4*>(row + 4);
        v[0] = a.x; v[1] = a.y; v[2] = a.z; v[3] = a.w;
        v[4] = b.x; v[5] = b.y; v[6] = b.z; v[7] = b.w;
    } else {
        const float4* trow = reinterpret_cast<const float4*>(typ_tab + (size_t)t * 8);
        const float4 a = trow[0];
        const float4 b = trow[1];
        v[0] = a.x; v[1] = a.y; v[2] = a.z; v[3] = a.w;
        v[4] = b.x; v[5] = b.y; v[6] = b.z; v[7] = b.w;
    }

    float s = 0.f, s2 = 0.f;
#pragma unroll
    for (int i = 0; i < 8; ++i) { s += v[i]; s2 += v[i] * v[i]; }

#pragma unroll
    for (int off = 32; off > 0; off >>= 1) {
        s  += __shfl_xor(s,  off, 64);
        s2 += __shfl_xor(s2, off, 64);
    }

    const float inv_n = 1.0f / (float)D_MODEL;
    const float mean  = s * inv_n;
    const float var   = s2 * inv_n - mean * mean;
    const float rs    = rsqrtf(var + EPS) * SQRT_D;

    const float4 g0 = *reinterpret_cast<const float4*>(gamma + lane * 8);
    const float4 g1 = *reinterpret_cast<const float4*>(gamma + lane * 8 + 4);
    const float4 b0 = *reinterpret_cast<const float4*>(beta  + lane * 8);
    const float4 b1 = *reinterpret_cast<const float4*>(beta  + lane * 8 + 4);

    float4 o0, o1;
    o0.x = (v[0] - mean) * rs * g0.x + b0.x * SQRT_D;
    o0.y = (v[1] - mean) * rs * g0.y + b0.y * SQRT_D;
    o0.z = (v[2] - mean) * rs * g0.z + b0.z * SQRT_D;
    o0.w = (v[3] - mean) * rs * g0.w + b0.w * SQRT_D;
    o1.x = (v[4] - mean) * rs * g1.x + b1.x * SQRT_D;
    o1.y = (v[5] - mean) * rs * g1.y + b1.y * SQRT_D;
    o1.z = (v[6] - mean) * rs * g1.z + b1.z * SQRT_D;
    o1.w = (v[7] - mean) * rs * g1.w + b1.w * SQRT_D;

    float* orow = uniq + (size_t)vid * D_MODEL + (size_t)lane * 8;
    *reinterpret_cast<float4*>(orow)     = o0;
    *reinterpret_cast<float4*>(orow + 4) = o1;
}

// ---------------------------------------------------------------------------
// Kernel 2: pure gather-copy. One wave per token; table is 4 MiB (L2/L3 hot).
// ---------------------------------------------------------------------------
__global__ __launch_bounds__(256) void gather_kernel(
    const int*   __restrict__ x,
    const float* __restrict__ uniq,      // [2048][512]
    float*       __restrict__ out,       // [n_tokens][512]
    int n_tokens)
{
    const int tok  = (int)((blockIdx.x * blockDim.x + threadIdx.x) >> 6);
    const int lane = (int)(threadIdx.x & 63);
    if (tok >= n_tokens) return;

    const int xi = __builtin_amdgcn_readfirstlane(x[tok]);

    const float* src = uniq + (size_t)xi * D_MODEL + (size_t)lane * 8;
    float*       dst = out  + (size_t)tok * D_MODEL + (size_t)lane * 8;

    const float4 a = *reinterpret_cast<const float4*>(src);
    const float4 b = *reinterpret_cast<const float4*>(src + 4);
    *reinterpret_cast<float4*>(dst)     = a;
    *reinterpret_cast<float4*>(dst + 4) = b;
}

// ---------------------------------------------------------------------------
// Fallback (ws too small): verified Round-1 fused kernel.
// ---------------------------------------------------------------------------
__global__ __launch_bounds__(256) void fused_kernel(
    const int*   __restrict__ x,
    const float* __restrict__ tok_tab,
    const float* __restrict__ typ_tab,
    const float* __restrict__ gamma,
    const float* __restrict__ beta,
    float*       __restrict__ out,
    int n_tokens)
{
    const int wave = (int)((blockIdx.x * blockDim.x + threadIdx.x) >> 6);
    const int lane = (int)(threadIdx.x & 63);
    if (wave >= n_tokens) return;

    const int xi = x[wave];
    const int t = (xi >= 128) + (xi >= 256) + (xi >= 512) + (xi >= 1024);

    float v[8];
    if (lane < 63) {
        const float* row = tok_tab + (size_t)xi * D_TOK + (size_t)lane * 8;
        const float4 a = *reinterpret_cast<const float4*>(row);
        const float4 b = *reinterpret_cast<const float4*>(row + 4);
        v[0] = a.x; v[1] = a.y; v[2] = a.z; v[3] = a.w;
        v[4] = b.x; v[5] = b.y; v[6] = b.z; v[7] = b.w;
    } else {
        const float4* trow = reinterpret_cast<const float4*>(typ_tab + (size_t)t * 8);
        const float4 a = trow[0];
        const float4 b = trow[1];
        v[0] = a.x; v[1] = a.y; v[2] = a.z; v[3] = a.w;
        v[4] = b.x; v[5] = b.y; v[6] = b.z; v[7] = b.w;
    }

    float s = 0.f, s2 = 0.f;
#pragma unroll
    for (int i = 0; i < 8; ++i) { s += v[i]; s2 += v[i] * v[i]; }
#pragma unroll
    for (int off = 32; off > 0; off >>= 1) {
        s  += __shfl_xor(s,  off, 64);
        s2 += __shfl_xor(s2, off, 64);
    }

    const float inv_n = 1.0f / (float)D_MODEL;
    const float mean  = s * inv_n;
    const float var   = s2 * inv_n - mean * mean;
    const float rs    = rsqrtf(var + EPS) * SQRT_D;

    const float4 g0 = *reinterpret_cast<const float4*>(gamma + lane * 8);
    const float4 g1 = *reinterpret_cast<const float4*>(gamma + lane * 8 + 4);
    const float4 b0 = *reinterpret_cast<const float4*>(beta  + lane * 8);
    const float4 b1 = *reinterpret_cast<const float4*>(beta  + lane * 8 + 4);

    float4 o0, o1;
    o0.x = (v[0] - mean) * rs * g0.x + b0.x * SQRT_D;
    o0.y = (v[1] - mean) * rs * g0.y + b0.y * SQRT_D;
    o0.z = (v[2] - mean) * rs * g0.z + b0.z * SQRT_D;
    o0.w = (v[3] - mean) * rs * g0.w + b0.w * SQRT_D;
    o1.x = (v[4] - mean) * rs * g1.x + b1.x * SQRT_D;
    o1.y = (v[5] - mean) * rs * g1.y + b1.y * SQRT_D;
    o1.z = (v[6] - mean) * rs * g1.z + b1.z * SQRT_D;
    o1.w = (v[7] - mean) * rs * g1.w + b1.w * SQRT_D;

    float* orow = out + (size_t)wave * D_MODEL + (size_t)lane * 8;
    *reinterpret_cast<float4*>(orow)     = o0;
    *reinterpret_cast<float4*>(orow + 4) = o1;
}

extern "C" void kernel_launch(void* const* d_in, const int* in_sizes, int n_in,
                              void* d_out, int out_size, void* d_ws, size_t ws_size,
                              hipStream_t stream) {
    const int*   x       = (const int*)d_in[0];
    const float* tok_tab = (const float*)d_in[1];
    const float* typ_tab = (const float*)d_in[2];
    const float* gamma   = (const float*)d_in[3];
    const float* beta    = (const float*)d_in[4];
    float*       out     = (float*)d_out;

    const int n_tokens = in_sizes[0];   // 65536
    const size_t need  = (size_t)VOCAB * D_MODEL * sizeof(float);  // 4 MiB

    if (ws_size >= need) {
        float* uniq = (float*)d_ws;
        // 1) precompute 2048 unique rows (2048 waves)
        build_table_kernel<<<(VOCAB * 64) / 256, 256, 0, stream>>>(
            tok_tab, typ_tab, gamma, beta, uniq);
        // 2) gather-copy (one wave per token)
        gather_kernel<<<(n_tokens * 64) / 256, 256, 0, stream>>>(
            x, uniq, out, n_tokens);
    } else {
        fused_kernel<<<(n_tokens * 64) / 256, 256, 0, stream>>>(
            x, tok_tab, typ_tab, gamma, beta, out, n_tokens);
    }
}